// Round 3
// baseline (377.979 us; speedup 1.0000x reference)
//
#include <hip/hip_runtime.h>

#define B_ 64
#define C_ 256
#define TV_ 1600
#define V_ 25
#define H_ 8

typedef __attribute__((ext_vector_type(2))) int   intx2;
typedef __attribute__((ext_vector_type(4))) int   intx4;
typedef __attribute__((ext_vector_type(4))) float floatx4;
typedef __attribute__((ext_vector_type(8))) short short8;

__device__ __forceinline__ unsigned short f2bf(float f) {
    union { float f; unsigned u; } c; c.f = f;
    unsigned u = c.u;
    u += 0x7fffu + ((u >> 16) & 1u);   // RNE (no NaN inputs in this problem)
    return (unsigned short)(u >> 16);
}
__device__ __forceinline__ int pk_bf2(float a, float b) {
    return (int)((unsigned)f2bf(a) | ((unsigned)f2bf(b) << 16));
}

// ---------------- Kz: zero OA32+L (blocks 0..527), cast vw/pw -> bf16 (blocks 528..591) ----
__global__ __launch_bounds__(256) void kz_zero(float* __restrict__ zbase,
        const float* __restrict__ vw, const float* __restrict__ pw,
        unsigned short* __restrict__ VWB, unsigned short* __restrict__ PWB) {
    const int blk = blockIdx.x;
    if (blk < 528) {
        const int i = blk * 256 + threadIdx.x;   // 528*256 = 135168 float4 = 2,162,688 B
        ((floatx4*)zbase)[i] = (floatx4){0.f, 0.f, 0.f, 0.f};
    } else {
        const int g = (blk - 528) * 256 + threadIdx.x;  // 0..16383, one float4 each
        const floatx4 v = ((const floatx4*)vw)[g];
        const floatx4 p = ((const floatx4*)pw)[g];
        ((intx2*)VWB)[g] = (intx2){pk_bf2(v[0], v[1]), pk_bf2(v[2], v[3])};
        ((intx2*)PWB)[g] = (intx2){pk_bf2(p[0], p[1]), pk_bf2(p[2], p[3])};
    }
}

// ---------------- K1: x_patch (B,C,1600) fp32 -> XNC (B,1600,256) bf16 ----------------
__global__ __launch_bounds__(256) void k1_trans(const float* __restrict__ xp,
                                                unsigned short* __restrict__ XNC) {
    __shared__ float xs[128 * 68];
    const int blk = blockIdx.x;
    const int b = blk / 25, nb = blk - b * 25;
    const int n0 = nb * 64;
    const int t = threadIdx.x;
    const int cl = t & 127, nh = (t >> 7) * 32;
    const int n = t & 63, cg = t >> 6;
    for (int p = 0; p < 2; p++) {
        const float* src = xp + ((size_t)(b * C_ + p * 128 + cl)) * TV_ + n0 + nh;
        floatx4 v[8];
        #pragma unroll
        for (int j = 0; j < 8; j++) v[j] = *(const floatx4*)(src + 4 * j);
        if (p) __syncthreads();
        #pragma unroll
        for (int j = 0; j < 8; j++) *(floatx4*)&xs[cl * 68 + nh + 4 * j] = v[j];
        __syncthreads();
        unsigned short* dst = XNC + ((size_t)(b * TV_ + n0 + n)) * C_ + p * 128 + cg * 32;
        #pragma unroll
        for (int j8 = 0; j8 < 4; j8++) {
            const int cb = cg * 32 + j8 * 8;
            intx4 w;
            w[0] = pk_bf2(xs[(cb + 0) * 68 + n], xs[(cb + 1) * 68 + n]);
            w[1] = pk_bf2(xs[(cb + 2) * 68 + n], xs[(cb + 3) * 68 + n]);
            w[2] = pk_bf2(xs[(cb + 4) * 68 + n], xs[(cb + 5) * 68 + n]);
            w[3] = pk_bf2(xs[(cb + 6) * 68 + n], xs[(cb + 7) * 68 + n]);
            *(intx4*)(dst + j8 * 8) = w;
        }
        if (!p) __syncthreads();
    }
}

// ---------------- K0: Qt[b,h,25,256] bf16 = temp[h]/sqrt(32)*log2e * (xc @ qw_h^T) @ kw_h ----
__global__ __launch_bounds__(256) void k0_qtilde(const float* __restrict__ xcls,
        const float* __restrict__ qw, const float* __restrict__ kw,
        const float* __restrict__ temp, unsigned short* __restrict__ QT) {
    __shared__ float xq[25 * 260];    // [q][c] pad 260 (1040B rows, 16B-aligned)
    __shared__ float qh[25 * 33];     // [q][d]
    __shared__ float kws[32 * 264];   // [d][c]
    const int blk = blockIdx.x;
    const int b = blk >> 3, h = blk & 7;
    const int t = threadIdx.x;
    {   // xcls[b][c][q] -> xq[q][c]
        const float* src = xcls + ((size_t)(b * C_ + t)) * V_;
        #pragma unroll
        for (int q = 0; q < V_; q++) xq[q * 260 + t] = src[q];
    }
    {
        const int d = t >> 3, c0 = (t & 7) * 32;
        const float* src = kw + (size_t)(h * 32 + d) * C_ + c0;
        #pragma unroll
        for (int j4 = 0; j4 < 8; j4++)
            *(floatx4*)&kws[d * 264 + c0 + 4 * j4] = *(const floatx4*)(src + 4 * j4);
    }
    __syncthreads();
    // qh[q][d] = dot(xq[q][:], qw[h*32+d][:]) -- float4 vectorized
    for (int idx = t; idx < 800; idx += 256) {
        const int q = idx >> 5, d = idx & 31;
        const float* qwr = qw + (size_t)(h * 32 + d) * C_;
        float acc = 0.f;
        for (int c4 = 0; c4 < 64; c4++) {
            const floatx4 a = *(const floatx4*)(qwr + 4 * c4);
            const floatx4 x = *(const floatx4*)&xq[q * 260 + 4 * c4];
            acc += a[0] * x[0] + a[1] * x[1] + a[2] * x[2] + a[3] * x[3];
        }
        qh[q * 33 + d] = acc;
    }
    __syncthreads();
    const float scale = temp[h] * 0.17677669529663689f * 1.4426950408889634f;
    const int qp = t & 31, cg = t >> 5;
    const int c0 = cg * 32;
    if (qp < 25) {
        float acc[32];
        #pragma unroll
        for (int j = 0; j < 32; j++) acc[j] = 0.f;
        for (int d = 0; d < 32; d++) {
            const float a = qh[qp * 33 + d];
            const float* kr = &kws[d * 264 + c0];
            #pragma unroll
            for (int j = 0; j < 32; j++) acc[j] += a * kr[j];
        }
        unsigned short* dst = QT + ((size_t)((b * H_ + h) * 25 + qp)) * C_ + c0;
        #pragma unroll
        for (int j8 = 0; j8 < 4; j8++) {
            intx4 w;
            w[0] = pk_bf2(scale * acc[j8 * 8 + 0], scale * acc[j8 * 8 + 1]);
            w[1] = pk_bf2(scale * acc[j8 * 8 + 2], scale * acc[j8 * 8 + 3]);
            w[2] = pk_bf2(scale * acc[j8 * 8 + 4], scale * acc[j8 * 8 + 5]);
            w[3] = pk_bf2(scale * acc[j8 * 8 + 6], scale * acc[j8 * 8 + 7]);
            *(intx4*)(dst + j8 * 8) = w;
        }
    }
}

// ---------------- K2: per (b,h,s): S=Qt@Xnc^T, P=exp2(S), V=Xnc@vw_h^T (fused), PV -> atomics
__global__ __launch_bounds__(256, 3) void k2_attn(
        const unsigned short* __restrict__ XNC, const unsigned short* __restrict__ QT,
        const unsigned short* __restrict__ VWB, float* __restrict__ OA32,
        float* __restrict__ Lsum) {
    __shared__ unsigned short P_s[2][32 * 72];
    __shared__ unsigned short V_s[2][32 * 72];

    const int blk = blockIdx.x;
    const int h = blk / 320;
    const int rem = blk - h * 320;
    const int b = rem / 5;
    const int s = rem - b * 5;
    const int tid = threadIdx.x;
    const int wv = tid >> 6, lane = tid & 63;
    const int quad = lane >> 4, l16 = lane & 15;

    // Q fragments (rows >=25 read finite garbage; those S-rows are discarded)
    short8 qf[2][8];
    {
        const unsigned short* qb = QT + (size_t)(b * H_ + h) * 25 * C_;
        #pragma unroll
        for (int mt = 0; mt < 2; mt++)
            #pragma unroll
            for (int ks = 0; ks < 8; ks++)
                qf[mt][ks] = *(const short8*)(qb + (mt * 16 + l16) * C_ + ks * 32 + quad * 8);
    }
    // v_w fragments straight from precomputed bf16 VWB (L2-hot, no conversion)
    short8 vwf[2][8];
    #pragma unroll
    for (int dt = 0; dt < 2; dt++)
        #pragma unroll
        for (int ks = 0; ks < 8; ks++)
            vwf[dt][ks] = *(const short8*)(VWB + (size_t)(h * 32 + dt * 16 + l16) * C_ + ks * 32 + quad * 8);

    floatx4 oc = {0.f, 0.f, 0.f, 0.f};
    float lsum[8];
    #pragma unroll
    for (int i = 0; i < 8; i++) lsum[i] = 0.f;
    const int mtv = wv & 1, dtv = wv >> 1;
    const unsigned short* xnc_b = XNC + ((size_t)(b * TV_ + s * 320)) * C_;

    for (int ti = 0; ti < 5; ti++) {
        const int par = ti & 1;
        floatx4 sc0 = {0.f,0.f,0.f,0.f}, sc1 = {0.f,0.f,0.f,0.f};
        floatx4 va0 = {0.f,0.f,0.f,0.f}, va1 = {0.f,0.f,0.f,0.f};
        {
            const unsigned short* xr = xnc_b + (size_t)(ti * 64 + wv * 16 + l16) * C_ + quad * 8;
            #pragma unroll
            for (int ks = 0; ks < 8; ks++) {
                const short8 bfv = *(const short8*)(xr + ks * 32);
                sc0 = __builtin_amdgcn_mfma_f32_16x16x32_bf16(qf[0][ks], bfv, sc0, 0, 0, 0);
                sc1 = __builtin_amdgcn_mfma_f32_16x16x32_bf16(qf[1][ks], bfv, sc1, 0, 0, 0);
                va0 = __builtin_amdgcn_mfma_f32_16x16x32_bf16(bfv, vwf[0][ks], va0, 0, 0, 0);
                va1 = __builtin_amdgcn_mfma_f32_16x16x32_bf16(bfv, vwf[1][ks], va1, 0, 0, 0);
            }
        }
        {
            const int colp = wv * 16 + l16;
            #pragma unroll
            for (int r = 0; r < 4; r++) {
                const float p0 = __builtin_amdgcn_exp2f(sc0[r]);
                const float p1 = __builtin_amdgcn_exp2f(sc1[r]);
                lsum[r] += p0;
                lsum[4 + r] += p1;
                P_s[par][(quad * 4 + r) * 72 + colp] = f2bf(p0);
                P_s[par][(16 + quad * 4 + r) * 72 + colp] = f2bf(p1);
                V_s[par][l16 * 72 + wv * 16 + quad * 4 + r] = f2bf(va0[r]);
                V_s[par][(16 + l16) * 72 + wv * 16 + quad * 4 + r] = f2bf(va1[r]);
            }
        }
        __syncthreads();
        #pragma unroll
        for (int ks2 = 0; ks2 < 2; ks2++) {
            const short8 a  = *(const short8*)&P_s[par][(mtv * 16 + l16) * 72 + ks2 * 32 + quad * 8];
            const short8 bv = *(const short8*)&V_s[par][(dtv * 16 + l16) * 72 + ks2 * 32 + quad * 8];
            oc = __builtin_amdgcn_mfma_f32_16x16x32_bf16(a, bv, oc, 0, 0, 0);
        }
    }
    #pragma unroll
    for (int i = 0; i < 8; i++) {
        float v = lsum[i];
        #pragma unroll
        for (int off = 1; off < 16; off <<= 1) v += __shfl_xor(v, off, 64);
        lsum[i] = v;
    }
    const size_t bh = (size_t)(b * H_ + h);
    if (l16 == 0) {
        #pragma unroll
        for (int mt = 0; mt < 2; mt++)
            #pragma unroll
            for (int r = 0; r < 4; r++) {
                const int q = mt * 16 + quad * 4 + r;
                if (q < 25) atomicAdd(&Lsum[bh * 32 + q], lsum[mt * 4 + r]);
            }
    }
    #pragma unroll
    for (int r = 0; r < 4; r++) {
        const int q = mtv * 16 + quad * 4 + r;
        if (q < 25)
            atomicAdd(&OA32[bh * 1024 + q * 32 + dtv * 16 + l16], oc[r]);
    }
}

// ---------------- K3 (MFMA): y[b,i,q] = pb[i] + sum_j pw[i,j] * OA32norm[b,q,j] ----------
__global__ __launch_bounds__(256) void k3_proj(const float* __restrict__ OA32,
        const float* __restrict__ Lsum, const unsigned short* __restrict__ PWB,
        const float* __restrict__ pb, float* __restrict__ y) {
    __shared__ unsigned short OB[32 * 264];   // normalized O, bf16, rows 25..31 zero
    __shared__ float rl_s[256];
    const int blk = blockIdx.x;
    const int b = blk >> 1, i0 = (blk & 1) * 128;
    const int t = threadIdx.x;
    const int wv = t >> 6, lane = t & 63;
    const int quad = lane >> 4, l16 = lane & 15;
    {
        const int h = t >> 5, q = t & 31;
        const float lv = Lsum[(size_t)(b * H_ + h) * 32 + q];
        rl_s[t] = (q < 25) ? 1.0f / lv : 0.0f;
    }
    __syncthreads();
    for (int idx = t; idx < 8192; idx += 256) {
        const int q = idx >> 8, j = idx & 255;
        const int h2 = j >> 5, d = j & 31;
        const float val = (q < 25)
            ? OA32[(size_t)(b * H_ + h2) * 1024 + q * 32 + d] * rl_s[h2 * 32 + q] : 0.f;
        OB[q * 264 + j] = f2bf(val);
    }
    __syncthreads();
    floatx4 oc[2][2];
    #pragma unroll
    for (int mt = 0; mt < 2; mt++)
        #pragma unroll
        for (int ntp = 0; ntp < 2; ntp++) oc[mt][ntp] = (floatx4){0.f, 0.f, 0.f, 0.f};
    #pragma unroll
    for (int ks = 0; ks < 8; ks++) {
        const short8 a0 = *(const short8*)&OB[l16 * 264 + ks * 32 + quad * 8];
        const short8 a1 = *(const short8*)&OB[(16 + l16) * 264 + ks * 32 + quad * 8];
        #pragma unroll
        for (int ntp = 0; ntp < 2; ntp++) {
            const int i = i0 + (wv * 2 + ntp) * 16 + l16;
            const short8 bv = *(const short8*)(PWB + (size_t)i * C_ + ks * 32 + quad * 8);
            oc[0][ntp] = __builtin_amdgcn_mfma_f32_16x16x32_bf16(a0, bv, oc[0][ntp], 0, 0, 0);
            oc[1][ntp] = __builtin_amdgcn_mfma_f32_16x16x32_bf16(a1, bv, oc[1][ntp], 0, 0, 0);
        }
    }
    #pragma unroll
    for (int ntp = 0; ntp < 2; ntp++) {
        const int i = i0 + (wv * 2 + ntp) * 16 + l16;
        const float bias = pb[i];
        #pragma unroll
        for (int mt = 0; mt < 2; mt++)
            #pragma unroll
            for (int r = 0; r < 4; r++) {
                const int q = mt * 16 + quad * 4 + r;
                if (q < 25) y[(size_t)b * 6400 + i * 25 + q] = oc[mt][ntp][r] + bias;
            }
    }
}

extern "C" void kernel_launch(void* const* d_in, const int* in_sizes, int n_in,
                              void* d_out, int out_size, void* d_ws, size_t ws_size,
                              hipStream_t stream) {
    const float* xcls = (const float*)d_in[0];
    const float* xp   = (const float*)d_in[1];
    const float* qw   = (const float*)d_in[2];
    const float* kw   = (const float*)d_in[3];
    const float* vw   = (const float*)d_in[4];
    const float* temp = (const float*)d_in[5];
    const float* pw   = (const float*)d_in[6];
    const float* pb   = (const float*)d_in[7];
    float* y = (float*)d_out;

    // ws: XNC 52,428,800 | QT 6,553,600 | OA32 2,097,152 | L 65,536 | VWB 131,072 | PWB 131,072
    if (ws_size < (size_t)61407232) return;
    char* ws = (char*)d_ws;
    unsigned short* XNC  = (unsigned short*)ws;
    unsigned short* QT   = (unsigned short*)(ws + 52428800);
    float*          OA32 = (float*)(ws + 58982400);
    float*          L    = (float*)(ws + 61079552);
    unsigned short* VWB  = (unsigned short*)(ws + 61145088);
    unsigned short* PWB  = (unsigned short*)(ws + 61276160);

    hipLaunchKernelGGL(kz_zero,  dim3(592),  dim3(256), 0, stream, OA32, vw, pw, VWB, PWB);
    hipLaunchKernelGGL(k1_trans, dim3(1600), dim3(256), 0, stream, xp, XNC);
    hipLaunchKernelGGL(k0_qtilde,dim3(512),  dim3(256), 0, stream, xcls, qw, kw, temp, QT);
    hipLaunchKernelGGL(k2_attn,  dim3(2560), dim3(256), 0, stream, XNC, QT, VWB, OA32, L);
    hipLaunchKernelGGL(k3_proj,  dim3(128),  dim3(256), 0, stream, OA32, L, PWB, pb, y);
}

// Round 4
// 299.357 us; speedup vs baseline: 1.2626x; 1.2626x over previous
//
#include <hip/hip_runtime.h>

#define B_ 64
#define C_ 256
#define TV_ 1600
#define V_ 25
#define H_ 8

typedef __attribute__((ext_vector_type(2))) int   intx2;
typedef __attribute__((ext_vector_type(4))) int   intx4;
typedef __attribute__((ext_vector_type(4))) float floatx4;
typedef __attribute__((ext_vector_type(8))) short short8;

__device__ __forceinline__ unsigned short f2bf(float f) {
    union { float f; unsigned u; } c; c.f = f;
    unsigned u = c.u;
    u += 0x7fffu + ((u >> 16) & 1u);   // RNE (no NaN inputs in this problem)
    return (unsigned short)(u >> 16);
}
__device__ __forceinline__ float bf2f(unsigned short s) {
    union { unsigned u; float f; } c; c.u = ((unsigned)s) << 16;
    return c.f;
}
__device__ __forceinline__ int pk_bf2(float a, float b) {
    return (int)((unsigned)f2bf(a) | ((unsigned)f2bf(b) << 16));
}

// ---------------- Kz: zero OA+L (blocks 0..527); cast vw/pw -> bf16 (blocks 528..591) ----
__global__ __launch_bounds__(256) void kz_zero(float* __restrict__ zbase,
        const float* __restrict__ vw, const float* __restrict__ pw,
        unsigned short* __restrict__ VWB, unsigned short* __restrict__ PWB) {
    const int blk = blockIdx.x;
    if (blk < 528) {
        const int i = blk * 256 + threadIdx.x;   // 528*256 = 135168 float4 = 2,162,688 B
        ((floatx4*)zbase)[i] = (floatx4){0.f, 0.f, 0.f, 0.f};
    } else {
        const int g = (blk - 528) * 256 + threadIdx.x;  // 16384 float4
        const floatx4 v = ((const floatx4*)vw)[g];
        const floatx4 p = ((const floatx4*)pw)[g];
        ((intx2*)VWB)[g] = (intx2){pk_bf2(v[0], v[1]), pk_bf2(v[2], v[3])};
        ((intx2*)PWB)[g] = (intx2){pk_bf2(p[0], p[1]), pk_bf2(p[2], p[3])};
    }
}

// ---------------- K1: x_patch (B,C,1600) fp32 -> XF frag-major bf16 ----------------
// XF chunk layout: chunk_idx = (b*50 + nt)*1024 + cg*32 + n32  (nt = n/32, cg = c/8,
// n32 = n%32); each chunk = 8 consecutive-c bf16 = 16 B. This is exactly the MFMA
// frag read order, so k2 stages tiles with coalesced 16B loads and zero repacking.
__global__ __launch_bounds__(256) void k1_trans(const float* __restrict__ xp,
                                                unsigned short* __restrict__ XF) {
    __shared__ float xs[128 * 68];
    const int blk = blockIdx.x;
    const int b = blk / 25, nb = blk - b * 25;
    const int n0 = nb * 64;
    const int t = threadIdx.x;
    const int cl = t & 127, nh = (t >> 7) * 32;
    const int n = t & 63, cq = t >> 6;
    for (int p = 0; p < 2; p++) {
        const float* src = xp + ((size_t)(b * C_ + p * 128 + cl)) * TV_ + n0 + nh;
        floatx4 v[8];
        #pragma unroll
        for (int j = 0; j < 8; j++) v[j] = *(const floatx4*)(src + 4 * j);
        if (p) __syncthreads();
        #pragma unroll
        for (int j = 0; j < 8; j++) *(floatx4*)&xs[cl * 68 + nh + 4 * j] = v[j];
        __syncthreads();
        #pragma unroll
        for (int j4 = 0; j4 < 4; j4++) {
            const int cgl = cq * 4 + j4, c8 = cgl * 8;
            intx4 w;
            w[0] = pk_bf2(xs[(c8 + 0) * 68 + n], xs[(c8 + 1) * 68 + n]);
            w[1] = pk_bf2(xs[(c8 + 2) * 68 + n], xs[(c8 + 3) * 68 + n]);
            w[2] = pk_bf2(xs[(c8 + 4) * 68 + n], xs[(c8 + 5) * 68 + n]);
            w[3] = pk_bf2(xs[(c8 + 6) * 68 + n], xs[(c8 + 7) * 68 + n]);
            const size_t chunk = (size_t)(b * 50 + nb * 2 + (n >> 5)) * 1024
                               + (p * 16 + cgl) * 32 + (n & 31);
            *(intx4*)(XF + chunk * 8) = w;
        }
        if (!p) __syncthreads();
    }
}

// ---------------- K0: Qt[b,h,25,256] bf16 = temp[h]/sqrt(32)*log2e * (xc @ qw_h^T) @ kw_h ----
__global__ __launch_bounds__(256) void k0_qtilde(const float* __restrict__ xcls,
        const float* __restrict__ qw, const float* __restrict__ kw,
        const float* __restrict__ temp, unsigned short* __restrict__ QT) {
    __shared__ float xq[25 * 260];    // [q][c]
    __shared__ float qh[25 * 33];     // [q][d]
    __shared__ float kws[32 * 264];   // [d][c]
    const int blk = blockIdx.x;
    const int b = blk >> 3, h = blk & 7;
    const int t = threadIdx.x;
    {
        const float* src = xcls + ((size_t)(b * C_ + t)) * V_;
        #pragma unroll
        for (int q = 0; q < V_; q++) xq[q * 260 + t] = src[q];
    }
    {
        const int d = t >> 3, c0 = (t & 7) * 32;
        const float* src = kw + (size_t)(h * 32 + d) * C_ + c0;
        #pragma unroll
        for (int j4 = 0; j4 < 8; j4++)
            *(floatx4*)&kws[d * 264 + c0 + 4 * j4] = *(const floatx4*)(src + 4 * j4);
    }
    __syncthreads();
    for (int idx = t; idx < 800; idx += 256) {
        const int q = idx >> 5, d = idx & 31;
        const float* qwr = qw + (size_t)(h * 32 + d) * C_;
        float acc = 0.f;
        for (int c4 = 0; c4 < 64; c4++) {
            const floatx4 a = *(const floatx4*)(qwr + 4 * c4);
            const floatx4 x = *(const floatx4*)&xq[q * 260 + 4 * c4];
            acc += a[0] * x[0] + a[1] * x[1] + a[2] * x[2] + a[3] * x[3];
        }
        qh[q * 33 + d] = acc;
    }
    __syncthreads();
    const float scale = temp[h] * 0.17677669529663689f * 1.4426950408889634f;
    const int qp = t & 31, cg = t >> 5;
    const int c0 = cg * 32;
    if (qp < 25) {
        floatx4 a4[8];
        #pragma unroll
        for (int j = 0; j < 8; j++) a4[j] = (floatx4){0.f, 0.f, 0.f, 0.f};
        for (int d = 0; d < 32; d++) {
            const float a = qh[qp * 33 + d];    // LDS same-addr broadcast within cg-group
            #pragma unroll
            for (int j4 = 0; j4 < 8; j4++) {
                const floatx4 k4 = *(const floatx4*)&kws[d * 264 + c0 + 4 * j4];
                a4[j4][0] += a * k4[0]; a4[j4][1] += a * k4[1];
                a4[j4][2] += a * k4[2]; a4[j4][3] += a * k4[3];
            }
        }
        unsigned short* dst = QT + ((size_t)((b * H_ + h) * 25 + qp)) * C_ + c0;
        #pragma unroll
        for (int j8 = 0; j8 < 4; j8++) {
            intx4 w;
            w[0] = pk_bf2(scale * a4[j8 * 2][0],     scale * a4[j8 * 2][1]);
            w[1] = pk_bf2(scale * a4[j8 * 2][2],     scale * a4[j8 * 2][3]);
            w[2] = pk_bf2(scale * a4[j8 * 2 + 1][0], scale * a4[j8 * 2 + 1][1]);
            w[3] = pk_bf2(scale * a4[j8 * 2 + 1][2], scale * a4[j8 * 2 + 1][3]);
            *(intx4*)(dst + j8 * 8) = w;
        }
    }
}

// ---------------- K2: block=(b, s of 160 n-rows), 8 waves = 8 heads, X shared via LDS ----
__global__ __launch_bounds__(512, 2) void k2_attn(
        const unsigned short* __restrict__ XF, const unsigned short* __restrict__ QT,
        const unsigned short* __restrict__ VWB, float* __restrict__ OA,
        float* __restrict__ L) {
    __shared__ unsigned short Xs[8192];        // 1024 chunks x 16B = 16 KB, frag-major
    __shared__ unsigned short Ps[8][32 * 40];  // per-head P  [q][n], pad 40
    __shared__ unsigned short Vs[8][32 * 40];  // per-head V^T [d][n], pad 40

    const int blk = blockIdx.x;
    const int b = blk & 63, s = blk >> 6;      // s in 0..9; s-twins of b share XCD (64%8==0)
    const int tid = threadIdx.x;
    const int h = tid >> 6;                    // wave == head
    const int lane = tid & 63;
    const int quad = lane >> 4, l16 = lane & 15;

    // Q~ A-frags (rows >=25 read adjacent data / pad: finite garbage, discarded)
    short8 qf[2][8];
    {
        const unsigned short* qb = QT + (size_t)(b * H_ + h) * 25 * C_;
        #pragma unroll
        for (int mt = 0; mt < 2; mt++)
            #pragma unroll
            for (int ks = 0; ks < 8; ks++)
                qf[mt][ks] = *(const short8*)(qb + (mt * 16 + l16) * C_ + ks * 32 + quad * 8);
    }
    // v_w B-frags for this head's 32 d-columns
    short8 vwf[2][8];
    #pragma unroll
    for (int dt = 0; dt < 2; dt++)
        #pragma unroll
        for (int ks = 0; ks < 8; ks++)
            vwf[dt][ks] = *(const short8*)(VWB + (size_t)(h * 32 + dt * 16 + l16) * C_ + ks * 32 + quad * 8);

    floatx4 oc[2][2];                           // [mt][dt]
    #pragma unroll
    for (int mt = 0; mt < 2; mt++)
        #pragma unroll
        for (int dt = 0; dt < 2; dt++) oc[mt][dt] = (floatx4){0.f, 0.f, 0.f, 0.f};
    float lsum[2][4];
    #pragma unroll
    for (int mt = 0; mt < 2; mt++)
        #pragma unroll
        for (int r = 0; r < 4; r++) lsum[mt][r] = 0.f;

    const unsigned short* xf_base = XF + (size_t)(b * 50 + s * 5) * 1024 * 8;
    intx4 px0 = *(const intx4*)(xf_base + (size_t)(tid * 2 + 0) * 8);
    intx4 px1 = *(const intx4*)(xf_base + (size_t)(tid * 2 + 1) * 8);

    for (int ti = 0; ti < 5; ti++) {
        *(intx4*)&Xs[(tid * 2 + 0) * 8] = px0;
        *(intx4*)&Xs[(tid * 2 + 1) * 8] = px1;
        __syncthreads();
        if (ti < 4) {   // prefetch next tile; vmcnt waited only at next iter's ds_write
            const unsigned short* nxt = xf_base + (size_t)(ti + 1) * 1024 * 8;
            px0 = *(const intx4*)(nxt + (size_t)(tid * 2 + 0) * 8);
            px1 = *(const intx4*)(nxt + (size_t)(tid * 2 + 1) * 8);
        }
        floatx4 sc[2][2], va[2][2];            // sc[mt][g], va[g][dt]
        #pragma unroll
        for (int i = 0; i < 2; i++)
            #pragma unroll
            for (int j = 0; j < 2; j++) {
                sc[i][j] = (floatx4){0.f, 0.f, 0.f, 0.f};
                va[i][j] = (floatx4){0.f, 0.f, 0.f, 0.f};
            }
        #pragma unroll
        for (int ks = 0; ks < 8; ks++) {
            const short8 xf0 = *(const short8*)&Xs[(((ks * 4 + quad) * 32) + l16) * 8];
            const short8 xf1 = *(const short8*)&Xs[(((ks * 4 + quad) * 32) + 16 + l16) * 8];
            sc[0][0] = __builtin_amdgcn_mfma_f32_16x16x32_bf16(qf[0][ks], xf0, sc[0][0], 0, 0, 0);
            sc[0][1] = __builtin_amdgcn_mfma_f32_16x16x32_bf16(qf[0][ks], xf1, sc[0][1], 0, 0, 0);
            sc[1][0] = __builtin_amdgcn_mfma_f32_16x16x32_bf16(qf[1][ks], xf0, sc[1][0], 0, 0, 0);
            sc[1][1] = __builtin_amdgcn_mfma_f32_16x16x32_bf16(qf[1][ks], xf1, sc[1][1], 0, 0, 0);
            va[0][0] = __builtin_amdgcn_mfma_f32_16x16x32_bf16(xf0, vwf[0][ks], va[0][0], 0, 0, 0);
            va[0][1] = __builtin_amdgcn_mfma_f32_16x16x32_bf16(xf0, vwf[1][ks], va[0][1], 0, 0, 0);
            va[1][0] = __builtin_amdgcn_mfma_f32_16x16x32_bf16(xf1, vwf[0][ks], va[1][0], 0, 0, 0);
            va[1][1] = __builtin_amdgcn_mfma_f32_16x16x32_bf16(xf1, vwf[1][ks], va[1][1], 0, 0, 0);
        }
        // P = exp2(S) -> wave-private LDS; V^T -> wave-private LDS (in-order DS, no barrier)
        #pragma unroll
        for (int mt = 0; mt < 2; mt++)
            #pragma unroll
            for (int g = 0; g < 2; g++)
                #pragma unroll
                for (int r = 0; r < 4; r++) {
                    const float p = __builtin_amdgcn_exp2f(sc[mt][g][r]);
                    lsum[mt][r] += p;
                    Ps[h][(mt * 16 + quad * 4 + r) * 40 + g * 16 + l16] = f2bf(p);
                }
        #pragma unroll
        for (int g = 0; g < 2; g++)
            #pragma unroll
            for (int dt = 0; dt < 2; dt++)
                *(intx2*)&Vs[h][(dt * 16 + l16) * 40 + g * 16 + quad * 4] =
                    (intx2){pk_bf2(va[g][dt][0], va[g][dt][1]),
                            pk_bf2(va[g][dt][2], va[g][dt][3])};
        // PV for this tile (K = 32 n-rows)
        #pragma unroll
        for (int mt = 0; mt < 2; mt++) {
            const short8 pa = *(const short8*)&Ps[h][(mt * 16 + l16) * 40 + quad * 8];
            #pragma unroll
            for (int dt = 0; dt < 2; dt++) {
                const short8 vb = *(const short8*)&Vs[h][(dt * 16 + l16) * 40 + quad * 8];
                oc[mt][dt] = __builtin_amdgcn_mfma_f32_16x16x32_bf16(pa, vb, oc[mt][dt], 0, 0, 0);
            }
        }
        __syncthreads();   // all waves done with Xs before next ds_write
    }
    // reduce lsum over the 16 columns (l16) of each quad
    #pragma unroll
    for (int mt = 0; mt < 2; mt++)
        #pragma unroll
        for (int r = 0; r < 4; r++) {
            float v = lsum[mt][r];
            #pragma unroll
            for (int off = 1; off < 16; off <<= 1) v += __shfl_xor(v, off, 64);
            lsum[mt][r] = v;
        }
    const size_t bh = (size_t)(b * H_ + h);
    if (l16 == 0) {
        #pragma unroll
        for (int mt = 0; mt < 2; mt++)
            #pragma unroll
            for (int r = 0; r < 4; r++) {
                const int q = mt * 16 + quad * 4 + r;
                if (q < 25) atomicAdd(&L[bh * 32 + q], lsum[mt][r]);
            }
    }
    #pragma unroll
    for (int mt = 0; mt < 2; mt++)
        #pragma unroll
        for (int dt = 0; dt < 2; dt++)
            #pragma unroll
            for (int r = 0; r < 4; r++) {
                const int q = mt * 16 + quad * 4 + r;
                if (q < 25)
                    atomicAdd(&OA[bh * 1024 + q * 32 + dt * 16 + l16], oc[mt][dt][r]);
            }
}

// ---------------- K3 (MFMA): y[b,i,q] = pb[i] + sum_j pw[i,j] * OAnorm[b,q,j] ----------
__global__ __launch_bounds__(256) void k3_proj(const float* __restrict__ OA,
        const float* __restrict__ Lsum, const unsigned short* __restrict__ PWB,
        const float* __restrict__ pb, float* __restrict__ y) {
    __shared__ unsigned short OB[32 * 264];   // normalized O bf16, rows 25..31 zero
    __shared__ float rl_s[256];
    const int blk = blockIdx.x;
    const int b = blk >> 1, i0 = (blk & 1) * 128;
    const int t = threadIdx.x;
    const int wv = t >> 6, lane = t & 63;
    const int quad = lane >> 4, l16 = lane & 15;
    {
        const int h = t >> 5, q = t & 31;
        const float lv = Lsum[(size_t)(b * H_ + h) * 32 + q];
        rl_s[t] = (q < 25) ? 1.0f / lv : 0.0f;
    }
    __syncthreads();
    for (int idx = t; idx < 8192; idx += 256) {
        const int q = idx >> 8, j = idx & 255;
        const int h2 = j >> 5, d = j & 31;
        const float val = (q < 25)
            ? OA[(size_t)(b * H_ + h2) * 1024 + q * 32 + d] * rl_s[h2 * 32 + q] : 0.f;
        OB[q * 264 + j] = f2bf(val);
    }
    __syncthreads();
    floatx4 oc[2][2];
    #pragma unroll
    for (int mt = 0; mt < 2; mt++)
        #pragma unroll
        for (int ntp = 0; ntp < 2; ntp++) oc[mt][ntp] = (floatx4){0.f, 0.f, 0.f, 0.f};
    #pragma unroll
    for (int ks = 0; ks < 8; ks++) {
        const short8 a0 = *(const short8*)&OB[l16 * 264 + ks * 32 + quad * 8];
        const short8 a1 = *(const short8*)&OB[(16 + l16) * 264 + ks * 32 + quad * 8];
        #pragma unroll
        for (int ntp = 0; ntp < 2; ntp++) {
            const int i = i0 + (wv * 2 + ntp) * 16 + l16;
            const short8 bv = *(const short8*)(PWB + (size_t)i * C_ + ks * 32 + quad * 8);
            oc[0][ntp] = __builtin_amdgcn_mfma_f32_16x16x32_bf16(a0, bv, oc[0][ntp], 0, 0, 0);
            oc[1][ntp] = __builtin_amdgcn_mfma_f32_16x16x32_bf16(a1, bv, oc[1][ntp], 0, 0, 0);
        }
    }
    #pragma unroll
    for (int ntp = 0; ntp < 2; ntp++) {
        const int i = i0 + (wv * 2 + ntp) * 16 + l16;
        const float bias = pb[i];
        #pragma unroll
        for (int mt = 0; mt < 2; mt++)
            #pragma unroll
            for (int r = 0; r < 4; r++) {
                const int q = mt * 16 + quad * 4 + r;
                if (q < 25) y[(size_t)b * 6400 + i * 25 + q] = oc[mt][ntp][r] + bias;
            }
    }
}

extern "C" void kernel_launch(void* const* d_in, const int* in_sizes, int n_in,
                              void* d_out, int out_size, void* d_ws, size_t ws_size,
                              hipStream_t stream) {
    const float* xcls = (const float*)d_in[0];
    const float* xp   = (const float*)d_in[1];
    const float* qw   = (const float*)d_in[2];
    const float* kw   = (const float*)d_in[3];
    const float* vw   = (const float*)d_in[4];
    const float* temp = (const float*)d_in[5];
    const float* pw   = (const float*)d_in[6];
    const float* pb   = (const float*)d_in[7];
    float* y = (float*)d_out;

    // ws: XF 52,428,800 | QT 6,553,600+8,192 pad | OA 2,097,152 | L 65,536 | VWB 131,072 | PWB 131,072
    if (ws_size < (size_t)61415424) return;
    char* ws = (char*)d_ws;
    unsigned short* XF  = (unsigned short*)ws;
    unsigned short* QT  = (unsigned short*)(ws + 52428800);
    float*          OA  = (float*)(ws + 58990592);
    float*          L   = (float*)(ws + 61087744);
    unsigned short* VWB = (unsigned short*)(ws + 61153280);
    unsigned short* PWB = (unsigned short*)(ws + 61284352);

    hipLaunchKernelGGL(kz_zero,  dim3(592),  dim3(256), 0, stream, OA, vw, pw, VWB, PWB);
    hipLaunchKernelGGL(k1_trans, dim3(1600), dim3(256), 0, stream, xp, XF);
    hipLaunchKernelGGL(k0_qtilde,dim3(512),  dim3(256), 0, stream, xcls, qw, kw, temp, QT);
    hipLaunchKernelGGL(k2_attn,  dim3(640),  dim3(512), 0, stream, XF, QT, VWB, OA, L);
    hipLaunchKernelGGL(k3_proj,  dim3(128),  dim3(256), 0, stream, OA, L, PWB, pb, y);
}